// Round 1
// baseline (569.505 us; speedup 1.0000x reference)
//
#include <hip/hip_runtime.h>
#include <math.h>

#define BB 2
#define LL 2048
#define DD 512
#define HH 8
#define DK 64
#define SK 40   // sample_k
#define UU 40   // top-k u
#define BH (BB*HH)   // 16

// ---------------- fill attns with 1/L ----------------
__global__ __launch_bounds__(256) void fill_attns(float* __restrict__ attns, long n4) {
    const float c = 1.0f / (float)LL;
    const float4 val = make_float4(c, c, c, c);
    float4* p = (float4*)attns;
    long stride = (long)gridDim.x * blockDim.x;
    for (long i = (long)blockIdx.x * blockDim.x + threadIdx.x; i < n4; i += stride)
        p[i] = val;
}

// ---------------- fused projection GEMM: P = x @ W^T + b, stored [b][h][l][d] ----------------
__global__ __launch_bounds__(256) void proj_gemm(
    const float* __restrict__ x,
    const float* __restrict__ Wq, const float* __restrict__ bq,
    const float* __restrict__ Wk, const float* __restrict__ bk,
    const float* __restrict__ Wv, const float* __restrict__ bv,
    float* __restrict__ q, float* __restrict__ k, float* __restrict__ v)
{
    const float* W; const float* bias; float* out;
    if (blockIdx.z == 0)      { W = Wq; bias = bq; out = q; }
    else if (blockIdx.z == 1) { W = Wk; bias = bk; out = k; }
    else                      { W = Wv; bias = bv; out = v; }

    __shared__ float As[64][17];
    __shared__ float Bs[16][65];
    const int n0 = blockIdx.x * 64;      // row tile over B*L = 4096
    const int o0 = blockIdx.y * 64;      // col tile over D = 512 (one head per tile)
    const int tid = threadIdx.x;
    const int tx = tid & 15, ty = tid >> 4;

    float acc[4][4] = {};

    for (int k0 = 0; k0 < DD; k0 += 16) {
        {   // x tile 64x16, one float4 per thread
            int row = tid >> 2, c4 = (tid & 3) * 4;
            const float4 xv = *(const float4*)&x[(long)(n0 + row) * DD + k0 + c4];
            As[row][c4 + 0] = xv.x; As[row][c4 + 1] = xv.y;
            As[row][c4 + 2] = xv.z; As[row][c4 + 3] = xv.w;
        }
        {   // W tile 64x16 -> transposed Bs[k][o]
            int o = tid >> 2, c4 = (tid & 3) * 4;
            const float4 wv = *(const float4*)&W[(long)(o0 + o) * DD + k0 + c4];
            Bs[c4 + 0][o] = wv.x; Bs[c4 + 1][o] = wv.y;
            Bs[c4 + 2][o] = wv.z; Bs[c4 + 3][o] = wv.w;
        }
        __syncthreads();
        #pragma unroll
        for (int kk = 0; kk < 16; ++kk) {
            float a[4], bbv[4];
            #pragma unroll
            for (int i = 0; i < 4; ++i) a[i] = As[ty * 4 + i][kk];
            #pragma unroll
            for (int j = 0; j < 4; ++j) bbv[j] = Bs[kk][tx * 4 + j];
            #pragma unroll
            for (int i = 0; i < 4; ++i)
                #pragma unroll
                for (int j = 0; j < 4; ++j) acc[i][j] += a[i] * bbv[j];
        }
        __syncthreads();
    }

    // epilogue: out[b][h][l][d], h == blockIdx.y
    const int h = blockIdx.y;
    const float4 bv4 = *(const float4*)&bias[h * DK + tx * 4];
    #pragma unroll
    for (int i = 0; i < 4; ++i) {
        int n = n0 + ty * 4 + i;
        int b_ = n >> 11, l = n & (LL - 1);
        float4 o4;
        o4.x = acc[i][0] + bv4.x; o4.y = acc[i][1] + bv4.y;
        o4.z = acc[i][2] + bv4.z; o4.w = acc[i][3] + bv4.w;
        *(float4*)&out[(((long)b_ * HH + h) * LL + l) * DK + tx * 4] = o4;
    }
}

// ---------------- sampled QK^T and M = max - sum/L ----------------
__global__ __launch_bounds__(256) void qk_sample_M(
    const float* __restrict__ q, const float* __restrict__ k,
    const int* __restrict__ idxs, float* __restrict__ M)
{
    // grid: BH * (L/64) = 512 blocks
    const int bh = blockIdx.x >> 5;
    const int l0 = (blockIdx.x & 31) * 64;
    __shared__ float qs[64][DK];
    __shared__ float qk[64][SK];
    const int tid = threadIdx.x;

    const float* qbase = q + ((long)bh * LL + l0) * DK;
    for (int f = tid; f < 64 * DK / 4; f += 256) {
        int row = f >> 4, c4 = (f & 15) * 4;
        *(float4*)&qs[row][c4] = *(const float4*)&qbase[row * DK + c4];
    }
    __syncthreads();

    const float* kbase = k + (long)bh * LL * DK;
    for (int p = tid; p < 64 * SK; p += 256) {
        int lloc = p / SK, s = p - lloc * SK;
        int idx = idxs[(l0 + lloc) * SK + s];
        const float* kr = kbase + (long)idx * DK;
        float acc = 0.f;
        #pragma unroll
        for (int c = 0; c < DK; c += 4) {
            float4 kv = *(const float4*)&kr[c];
            acc += qs[lloc][c] * kv.x + qs[lloc][c + 1] * kv.y
                 + qs[lloc][c + 2] * kv.z + qs[lloc][c + 3] * kv.w;
        }
        qk[lloc][s] = acc;
    }
    __syncthreads();

    if (tid < 64) {
        float mx = -INFINITY, sm = 0.f;
        #pragma unroll
        for (int s = 0; s < SK; ++s) { float t = qk[tid][s]; mx = fmaxf(mx, t); sm += t; }
        M[(long)bh * LL + l0 + tid] = mx - sm / (float)LL;
    }
}

// ---------------- top-40 per (b,h) via 40x argmax ----------------
__global__ __launch_bounds__(256) void topk_M(const float* __restrict__ M, int* __restrict__ Mtop)
{
    const int bh = blockIdx.x;
    __shared__ float m[LL];
    __shared__ float rv[256];
    __shared__ int   ri[256];
    const int tid = threadIdx.x;
    for (int i = tid; i < LL; i += 256) m[i] = M[(long)bh * LL + i];
    __syncthreads();
    for (int it = 0; it < UU; ++it) {
        float bv = -INFINITY; int bi = 0x7fffffff;
        for (int i = tid; i < LL; i += 256) {
            float val = m[i];
            if (val > bv) { bv = val; bi = i; }   // keeps lowest index among equals
        }
        rv[tid] = bv; ri[tid] = bi;
        __syncthreads();
        for (int s = 128; s > 0; s >>= 1) {
            if (tid < s) {
                float ov = rv[tid + s]; int oi = ri[tid + s];
                if (ov > rv[tid] || (ov == rv[tid] && oi < ri[tid])) { rv[tid] = ov; ri[tid] = oi; }
            }
            __syncthreads();
        }
        if (tid == 0) { Mtop[bh * UU + it] = ri[0]; m[ri[0]] = -INFINITY; }
        __syncthreads();
    }
}

// ---------------- per selected query: scores, softmax, upd, attn row ----------------
__global__ __launch_bounds__(256) void attn_topq(
    const float* __restrict__ q, const float* __restrict__ k,
    const float* __restrict__ v, const int* __restrict__ Mtop,
    float* __restrict__ upd, float* __restrict__ attns)
{
    const int bh = blockIdx.x / UU, u = blockIdx.x % UU;
    const int lsel = Mtop[bh * UU + u];
    __shared__ float qr[DK];
    __shared__ float sc[LL];
    __shared__ float red[256];
    const int tid = threadIdx.x;
    if (tid < DK) qr[tid] = q[((long)bh * LL + lsel) * DK + tid];
    __syncthreads();

    const float* kbase = k + (long)bh * LL * DK;
    const int lane = tid & 63, wave = tid >> 6;
    const float scale = 0.125f;  // 1/sqrt(64)

    for (int l = wave; l < LL; l += 4) {
        float p = qr[lane] * kbase[(long)l * DK + lane];
        #pragma unroll
        for (int s = 32; s > 0; s >>= 1) p += __shfl_down(p, s, 64);
        if (lane == 0) sc[l] = p * scale;
    }
    __syncthreads();

    // softmax over L
    float lm = -INFINITY;
    for (int i = tid; i < LL; i += 256) lm = fmaxf(lm, sc[i]);
    red[tid] = lm; __syncthreads();
    for (int s = 128; s > 0; s >>= 1) { if (tid < s) red[tid] = fmaxf(red[tid], red[tid + s]); __syncthreads(); }
    float mx = red[0]; __syncthreads();
    float ls = 0.f;
    for (int i = tid; i < LL; i += 256) { float e = expf(sc[i] - mx); sc[i] = e; ls += e; }
    red[tid] = ls; __syncthreads();
    for (int s = 128; s > 0; s >>= 1) { if (tid < s) red[tid] += red[tid + s]; __syncthreads(); }
    float inv = 1.0f / red[0]; __syncthreads();
    for (int i = tid; i < LL; i += 256) sc[i] *= inv;
    __syncthreads();

    // write attn row into attns[b,h,lsel,:]
    float* arow = attns + ((long)bh * LL + lsel) * LL;
    for (int i = tid; i < LL; i += 256) arow[i] = sc[i];

    // upd[u,d] = sum_l attn[l] * v[l,d]
    const float* vbase = v + (long)bh * LL * DK;
    const int d = tid & 63, part = tid >> 6;
    float acc = 0.f;
    const int lstart = part * (LL / 4);
    for (int l = lstart; l < lstart + LL / 4; ++l)
        acc += sc[l] * vbase[(long)l * DK + d];
    red[tid] = acc; __syncthreads();
    if (tid < 64) {
        float s = red[tid] + red[tid + 64] + red[tid + 128] + red[tid + 192];
        upd[((long)blockIdx.x) * DK + tid] = s;
    }
}

// ---------------- cumsum of v over l, per (b,h) ----------------
__global__ __launch_bounds__(256) void cumsum_v(const float* __restrict__ v, float* __restrict__ ctx)
{
    const int bh = blockIdx.x;
    __shared__ float csum[4][DK];
    const int tid = threadIdx.x;
    const int d = tid & 63, part = tid >> 6;
    const float* vb = v + (long)bh * LL * DK + d;
    float s = 0.f;
    const int l0 = part * (LL / 4);
    for (int l = l0; l < l0 + LL / 4; ++l) s += vb[(long)l * DK];
    csum[part][d] = s;
    __syncthreads();
    float carry = 0.f;
    for (int pp = 0; pp < part; ++pp) carry += csum[pp][d];
    float* cb = ctx + (long)bh * LL * DK + d;
    float run = carry;
    for (int l = l0; l < l0 + LL / 4; ++l) { run += vb[(long)l * DK]; cb[(long)l * DK] = run; }
}

// ---------------- scatter upd rows into context ----------------
__global__ __launch_bounds__(64) void scatter_upd(
    const int* __restrict__ Mtop, const float* __restrict__ upd, float* __restrict__ ctx)
{
    const int g = blockIdx.x;           // BH*UU
    const int bh = g / UU;
    const int lsel = Mtop[g];
    ctx[((long)bh * LL + lsel) * DK + threadIdx.x] = upd[(long)g * DK + threadIdx.x];
}

extern "C" void kernel_launch(void* const* d_in, const int* in_sizes, int n_in,
                              void* d_out, int out_size, void* d_ws, size_t ws_size,
                              hipStream_t stream) {
    const float* x  = (const float*)d_in[0];
    const float* Wq = (const float*)d_in[1];
    const float* bq = (const float*)d_in[2];
    const float* Wk = (const float*)d_in[3];
    const float* bk = (const float*)d_in[4];
    const float* Wv = (const float*)d_in[5];
    const float* bv = (const float*)d_in[6];
    const int* idxs = (const int*)d_in[7];

    float* ctx   = (float*)d_out;                            // B*H*L*DK = 2,097,152
    float* attns = (float*)d_out + (long)BB * HH * LL * DK;  // B*H*L*L  = 67,108,864

    char* w = (char*)d_ws;
    float* q    = (float*)w; w += (size_t)BB * HH * LL * DK * 4;
    float* k    = (float*)w; w += (size_t)BB * HH * LL * DK * 4;
    float* v    = (float*)w; w += (size_t)BB * HH * LL * DK * 4;
    float* M    = (float*)w; w += (size_t)BB * HH * LL * 4;
    int*   Mtop = (int*)w;   w += (size_t)BB * HH * UU * 4;
    float* upd  = (float*)w; w += (size_t)BB * HH * UU * DK * 4;

    // 1) fill attns with 1/L (independent of everything else)
    fill_attns<<<4096, 256, 0, stream>>>(attns, (long)BB * HH * LL * LL / 4);

    // 2) projections q,k,v (fp32 for exact-enough top-k ranking)
    dim3 g1(4096 / 64, DD / 64, 3);
    proj_gemm<<<g1, 256, 0, stream>>>(x, Wq, bq, Wk, bk, Wv, bv, q, k, v);

    // 3) sampled QK^T -> M
    qk_sample_M<<<BH * (LL / 64), 256, 0, stream>>>(q, k, idxs, M);

    // 4) top-40 indices per (b,h)
    topk_M<<<BH, 256, 0, stream>>>(M, Mtop);

    // 5) full attention for selected queries (writes upd + attn rows)
    attn_topq<<<BH * UU, 256, 0, stream>>>(q, k, v, Mtop, upd, attns);

    // 6) context = cumsum(v)
    cumsum_v<<<BH, 256, 0, stream>>>(v, ctx);

    // 7) overwrite selected context rows with upd
    scatter_upd<<<BH * UU, 64, 0, stream>>>(Mtop, upd, ctx);
}

// Round 2
// 301.666 us; speedup vs baseline: 1.8879x; 1.8879x over previous
//
#include <hip/hip_runtime.h>
#include <math.h>

#define BB 2
#define LL 2048
#define DD 512
#define HH 8
#define DK 64
#define SK 40   // sample_k
#define UU 40   // top-k u
#define BH (BB*HH)   // 16

// ---------------- fill attns with 1/L ----------------
__global__ __launch_bounds__(256) void fill_attns(float* __restrict__ attns, long n4) {
    const float c = 1.0f / (float)LL;
    const float4 val = make_float4(c, c, c, c);
    float4* p = (float4*)attns;
    long stride = (long)gridDim.x * blockDim.x;
    for (long i = (long)blockIdx.x * blockDim.x + threadIdx.x; i < n4; i += stride)
        p[i] = val;
}

// ---------------- fused projection GEMM: 128x128 tile, 8x8 micro-tile ----------------
__global__ __launch_bounds__(256) void proj_gemm(
    const float* __restrict__ x,
    const float* __restrict__ Wq, const float* __restrict__ bq,
    const float* __restrict__ Wk, const float* __restrict__ bk,
    const float* __restrict__ Wv, const float* __restrict__ bv,
    float* __restrict__ q, float* __restrict__ k, float* __restrict__ v)
{
    const float* W; const float* bias; float* out;
    if (blockIdx.z == 0)      { W = Wq; bias = bq; out = q; }
    else if (blockIdx.z == 1) { W = Wk; bias = bk; out = k; }
    else                      { W = Wv; bias = bv; out = v; }

    __shared__ float As[16][132];   // [k][row], transposed for contiguous fragment reads
    __shared__ float Bs[16][132];   // [k][col]
    const int n0 = blockIdx.x * 128;     // rows over B*L = 4096
    const int o0 = blockIdx.y * 128;     // cols over D = 512
    const int tid = threadIdx.x;
    const int tx = tid & 15, ty = tid >> 4;

    float acc[8][8] = {};

    for (int k0 = 0; k0 < DD; k0 += 16) {
        #pragma unroll
        for (int f = tid; f < 512; f += 256) {   // x tile 128x16
            int row = f >> 2, c4 = (f & 3) * 4;
            const float4 xv = *(const float4*)&x[(long)(n0 + row) * DD + k0 + c4];
            As[c4 + 0][row] = xv.x; As[c4 + 1][row] = xv.y;
            As[c4 + 2][row] = xv.z; As[c4 + 3][row] = xv.w;
        }
        #pragma unroll
        for (int f = tid; f < 512; f += 256) {   // W tile 128x16
            int o = f >> 2, c4 = (f & 3) * 4;
            const float4 wv = *(const float4*)&W[(long)(o0 + o) * DD + k0 + c4];
            Bs[c4 + 0][o] = wv.x; Bs[c4 + 1][o] = wv.y;
            Bs[c4 + 2][o] = wv.z; Bs[c4 + 3][o] = wv.w;
        }
        __syncthreads();
        #pragma unroll
        for (int kk = 0; kk < 16; ++kk) {
            float a[8], b[8];
            *(float4*)&a[0] = *(const float4*)&As[kk][ty * 8];
            *(float4*)&a[4] = *(const float4*)&As[kk][ty * 8 + 4];
            *(float4*)&b[0] = *(const float4*)&Bs[kk][tx * 8];
            *(float4*)&b[4] = *(const float4*)&Bs[kk][tx * 8 + 4];
            #pragma unroll
            for (int i = 0; i < 8; ++i)
                #pragma unroll
                for (int j = 0; j < 8; ++j) acc[i][j] += a[i] * b[j];
        }
        __syncthreads();
    }

    // epilogue
    const int col0 = o0 + tx * 8;
    const int h = col0 >> 6, d0 = col0 & 63;
    float br[8];
    #pragma unroll
    for (int j = 0; j < 8; ++j) br[j] = bias[col0 + j];
    #pragma unroll
    for (int i = 0; i < 8; ++i) {
        int n = n0 + ty * 8 + i;
        int b_ = n >> 11, l = n & (LL - 1);
        float* orow = out + (((long)b_ * HH + h) * LL + l) * DK + d0;
        float4 o0v, o1v;
        o0v.x = acc[i][0] + br[0]; o0v.y = acc[i][1] + br[1];
        o0v.z = acc[i][2] + br[2]; o0v.w = acc[i][3] + br[3];
        o1v.x = acc[i][4] + br[4]; o1v.y = acc[i][5] + br[5];
        o1v.z = acc[i][6] + br[6]; o1v.w = acc[i][7] + br[7];
        *(float4*)&orow[0] = o0v;
        *(float4*)&orow[4] = o1v;
    }
}

// ---------------- sampled QK^T and M = max - sum/L ----------------
__global__ __launch_bounds__(256) void qk_sample_M(
    const float* __restrict__ q, const float* __restrict__ k,
    const int* __restrict__ idxs, float* __restrict__ M)
{
    const int bh = blockIdx.x >> 5;
    const int l0 = (blockIdx.x & 31) * 64;
    __shared__ float qs[64][DK];
    __shared__ float qk[64][SK];
    const int tid = threadIdx.x;

    const float* qbase = q + ((long)bh * LL + l0) * DK;
    for (int f = tid; f < 64 * DK / 4; f += 256) {
        int row = f >> 4, c4 = (f & 15) * 4;
        *(float4*)&qs[row][c4] = *(const float4*)&qbase[row * DK + c4];
    }
    __syncthreads();

    const float* kbase = k + (long)bh * LL * DK;
    for (int p = tid; p < 64 * SK; p += 256) {
        int lloc = p / SK, s = p - lloc * SK;
        int idx = idxs[(l0 + lloc) * SK + s];
        const float* kr = kbase + (long)idx * DK;
        float acc = 0.f;
        #pragma unroll
        for (int c = 0; c < DK; c += 4) {
            float4 kv = *(const float4*)&kr[c];
            acc += qs[lloc][c] * kv.x + qs[lloc][c + 1] * kv.y
                 + qs[lloc][c + 2] * kv.z + qs[lloc][c + 3] * kv.w;
        }
        qk[lloc][s] = acc;
    }
    __syncthreads();

    if (tid < 64) {
        float mx = -INFINITY, sm = 0.f;
        #pragma unroll
        for (int s = 0; s < SK; ++s) { float t = qk[tid][s]; mx = fmaxf(mx, t); sm += t; }
        M[(long)bh * LL + l0 + tid] = mx - sm / (float)LL;
    }
}

// ---------------- top-40 per (b,h), wave-shuffle argmax loop ----------------
__global__ __launch_bounds__(256) void topk_M(const float* __restrict__ M, int* __restrict__ Mtop)
{
    const int bh = blockIdx.x;
    __shared__ float m[LL];
    __shared__ float wv_s[4];
    __shared__ int   wi_s[4];
    const int tid = threadIdx.x;
    const int lane = tid & 63, wave = tid >> 6;
    for (int i = tid; i < LL; i += 256) m[i] = M[(long)bh * LL + i];
    __syncthreads();
    for (int it = 0; it < UU; ++it) {
        float bv = -INFINITY; int bi = 0x7fffffff;
        #pragma unroll
        for (int r = 0; r < LL / 256; ++r) {
            int i = tid + r * 256;
            float val = m[i];
            if (val > bv) { bv = val; bi = i; }
        }
        #pragma unroll
        for (int s = 32; s > 0; s >>= 1) {
            float ov = __shfl_down(bv, s, 64);
            int   oi = __shfl_down(bi, s, 64);
            if (ov > bv || (ov == bv && oi < bi)) { bv = ov; bi = oi; }
        }
        if (lane == 0) { wv_s[wave] = bv; wi_s[wave] = bi; }
        __syncthreads();
        if (tid == 0) {
            float fv = wv_s[0]; int fi = wi_s[0];
            #pragma unroll
            for (int w = 1; w < 4; ++w) {
                float ov = wv_s[w]; int oi = wi_s[w];
                if (ov > fv || (ov == fv && oi < fi)) { fv = ov; fi = oi; }
            }
            Mtop[bh * UU + it] = fi;
            m[fi] = -INFINITY;
        }
        __syncthreads();
    }
}

// ---------------- scores for selected queries, written into attns rows ----------------
__global__ __launch_bounds__(256) void scores_topq(
    const float* __restrict__ q, const float* __restrict__ k,
    const int* __restrict__ Mtop, float* __restrict__ attns)
{
    const int bh = blockIdx.x >> 4;
    const int l0 = (blockIdx.x & 15) * 128;
    __shared__ int mt[UU];
    __shared__ float qs[UU][DK];
    const int tid = threadIdx.x;

    if (tid < UU) mt[tid] = Mtop[bh * UU + tid];
    __syncthreads();
    for (int f = tid; f < UU * DK / 4; f += 256) {   // 640 float4
        int u = f >> 4, c4 = (f & 15) * 4;
        *(float4*)&qs[u][c4] = *(const float4*)&q[((long)bh * LL + mt[u]) * DK + c4];
    }
    __syncthreads();

    const int tx = tid & 31, ty = tid >> 5;
    const float* kb = k + ((long)bh * LL + l0 + tx * 4) * DK;
    float acc[5][4] = {};
    #pragma unroll
    for (int d0 = 0; d0 < DK; d0 += 4) {
        float4 kv0 = *(const float4*)&kb[0 * DK + d0];
        float4 kv1 = *(const float4*)&kb[1 * DK + d0];
        float4 kv2 = *(const float4*)&kb[2 * DK + d0];
        float4 kv3 = *(const float4*)&kb[3 * DK + d0];
        #pragma unroll
        for (int i = 0; i < 5; ++i) {
            float4 q4 = *(const float4*)&qs[ty + 8 * i][d0];
            acc[i][0] += q4.x * kv0.x + q4.y * kv0.y + q4.z * kv0.z + q4.w * kv0.w;
            acc[i][1] += q4.x * kv1.x + q4.y * kv1.y + q4.z * kv1.z + q4.w * kv1.w;
            acc[i][2] += q4.x * kv2.x + q4.y * kv2.y + q4.z * kv2.z + q4.w * kv2.w;
            acc[i][3] += q4.x * kv3.x + q4.y * kv3.y + q4.z * kv3.z + q4.w * kv3.w;
        }
    }
    const float scale = 0.125f;
    #pragma unroll
    for (int i = 0; i < 5; ++i) {
        int u = ty + 8 * i;
        float4 o4;
        o4.x = acc[i][0] * scale; o4.y = acc[i][1] * scale;
        o4.z = acc[i][2] * scale; o4.w = acc[i][3] * scale;
        *(float4*)&attns[((long)bh * LL + mt[u]) * LL + l0 + tx * 4] = o4;
    }
}

// ---------------- softmax over each selected row (in place in attns) ----------------
__global__ __launch_bounds__(256) void softmax_rows(
    const int* __restrict__ Mtop, float* __restrict__ attns)
{
    const int g = blockIdx.x;            // BH*UU
    const int bh = g / UU;
    const int lsel = Mtop[g];
    float* row = attns + ((long)bh * LL + lsel) * LL;
    const int tid = threadIdx.x;
    const int lane = tid & 63, wave = tid >> 6;
    __shared__ float redm[4];
    __shared__ float reds[4];

    float4 v0 = *(float4*)&row[tid * 4];
    float4 v1 = *(float4*)&row[(tid + 256) * 4];

    float lm = fmaxf(fmaxf(fmaxf(v0.x, v0.y), fmaxf(v0.z, v0.w)),
                     fmaxf(fmaxf(v1.x, v1.y), fmaxf(v1.z, v1.w)));
    #pragma unroll
    for (int s = 32; s > 0; s >>= 1) lm = fmaxf(lm, __shfl_down(lm, s, 64));
    if (lane == 0) redm[wave] = lm;
    __syncthreads();
    const float mx = fmaxf(fmaxf(redm[0], redm[1]), fmaxf(redm[2], redm[3]));

    v0.x = expf(v0.x - mx); v0.y = expf(v0.y - mx);
    v0.z = expf(v0.z - mx); v0.w = expf(v0.w - mx);
    v1.x = expf(v1.x - mx); v1.y = expf(v1.y - mx);
    v1.z = expf(v1.z - mx); v1.w = expf(v1.w - mx);
    float ls = v0.x + v0.y + v0.z + v0.w + v1.x + v1.y + v1.z + v1.w;
    #pragma unroll
    for (int s = 32; s > 0; s >>= 1) ls += __shfl_down(ls, s, 64);
    if (lane == 0) reds[wave] = ls;
    __syncthreads();
    const float inv = 1.0f / (reds[0] + reds[1] + reds[2] + reds[3]);

    v0.x *= inv; v0.y *= inv; v0.z *= inv; v0.w *= inv;
    v1.x *= inv; v1.y *= inv; v1.z *= inv; v1.w *= inv;
    *(float4*)&row[tid * 4] = v0;
    *(float4*)&row[(tid + 256) * 4] = v1;
}

// ---------------- upd partial: per (bh, l-chunk) 40x64 partial GEMM ----------------
__global__ __launch_bounds__(256) void upd_partial(
    const float* __restrict__ v, const int* __restrict__ Mtop,
    const float* __restrict__ attns, float* __restrict__ partial)
{
    const int bh = blockIdx.x >> 4;
    const int ch = blockIdx.x & 15;
    const int l0 = ch * 128;
    __shared__ int mt[UU];
    __shared__ float pl[UU][128];
    __shared__ float vl[128][DK];
    const int tid = threadIdx.x;

    if (tid < UU) mt[tid] = Mtop[bh * UU + tid];
    __syncthreads();
    for (int f = tid; f < UU * 32; f += 256) {       // probs tile 40x128
        int u = f >> 5, l4 = (f & 31) * 4;
        *(float4*)&pl[u][l4] = *(const float4*)&attns[((long)bh * LL + mt[u]) * LL + l0 + l4];
    }
    for (int f = tid; f < 128 * 16; f += 256) {      // v tile 128x64
        int l = f >> 4, c4 = (f & 15) * 4;
        *(float4*)&vl[l][c4] = *(const float4*)&v[((long)bh * LL + l0 + l) * DK + c4];
    }
    __syncthreads();

    const int d = tid & 63, uu = tid >> 6;           // u is wave-uniform -> LDS broadcast
    float acc[10] = {};
    for (int l = 0; l < 128; ++l) {
        float vv = vl[l][d];
        #pragma unroll
        for (int i = 0; i < 10; ++i) acc[i] += pl[uu * 10 + i][l] * vv;
    }
    #pragma unroll
    for (int i = 0; i < 10; ++i) {
        int u = uu * 10 + i;
        partial[((long)blockIdx.x * UU + u) * DK + d] = acc[i];
    }
}

// ---------------- cumsum of v: 3-phase ----------------
__global__ __launch_bounds__(256) void cumsum_p1(const float* __restrict__ v, float* __restrict__ sums)
{
    const int bh = blockIdx.x;
    const int d = threadIdx.x & 63, sc = threadIdx.x >> 6;
    const int chunk = blockIdx.y * 4 + sc;
    const float* vb = v + ((long)bh * LL + chunk * 32) * DK + d;
    float s = 0.f;
    #pragma unroll
    for (int r = 0; r < 32; ++r) s += vb[r * DK];
    sums[((long)bh * 64 + chunk) * DK + d] = s;
}

__global__ __launch_bounds__(64) void cumsum_p2(float* __restrict__ sums)
{
    const int bh = blockIdx.x, d = threadIdx.x;
    float run = 0.f;
    for (int c = 0; c < 64; ++c) {
        long idx = ((long)bh * 64 + c) * DK + d;
        float t = sums[idx];
        sums[idx] = run;
        run += t;
    }
}

__global__ __launch_bounds__(256) void cumsum_p3(
    const float* __restrict__ v, const float* __restrict__ sums, float* __restrict__ ctx)
{
    const int bh = blockIdx.x;
    const int d = threadIdx.x & 63, sc = threadIdx.x >> 6;
    const int chunk = blockIdx.y * 4 + sc;
    const float* vb = v + ((long)bh * LL + chunk * 32) * DK + d;
    float* cb = ctx + ((long)bh * LL + chunk * 32) * DK + d;
    float run = sums[((long)bh * 64 + chunk) * DK + d];
    #pragma unroll
    for (int r = 0; r < 32; ++r) { run += vb[r * DK]; cb[r * DK] = run; }
}

// ---------------- reduce partials and scatter into ctx ----------------
__global__ __launch_bounds__(64) void reduce_scatter(
    const int* __restrict__ Mtop, const float* __restrict__ partial, float* __restrict__ ctx)
{
    const int g = blockIdx.x;           // BH*UU
    const int bh = g / UU, u = g - bh * UU;
    const int lsel = Mtop[g];
    const int d = threadIdx.x;
    float s = 0.f;
    #pragma unroll
    for (int ch = 0; ch < 16; ++ch)
        s += partial[(((long)(bh * 16 + ch)) * UU + u) * DK + d];
    ctx[((long)bh * LL + lsel) * DK + d] = s;
}

extern "C" void kernel_launch(void* const* d_in, const int* in_sizes, int n_in,
                              void* d_out, int out_size, void* d_ws, size_t ws_size,
                              hipStream_t stream) {
    const float* x  = (const float*)d_in[0];
    const float* Wq = (const float*)d_in[1];
    const float* bq = (const float*)d_in[2];
    const float* Wk = (const float*)d_in[3];
    const float* bk = (const float*)d_in[4];
    const float* Wv = (const float*)d_in[5];
    const float* bv = (const float*)d_in[6];
    const int* idxs = (const int*)d_in[7];

    float* ctx   = (float*)d_out;                            // B*H*L*DK
    float* attns = (float*)d_out + (long)BB * HH * LL * DK;  // B*H*L*L

    char* w = (char*)d_ws;
    float* q       = (float*)w; w += (size_t)BB * HH * LL * DK * 4;
    float* k       = (float*)w; w += (size_t)BB * HH * LL * DK * 4;
    float* v       = (float*)w; w += (size_t)BB * HH * LL * DK * 4;
    float* M       = (float*)w; w += (size_t)BB * HH * LL * 4;
    int*   Mtop    = (int*)w;   w += (size_t)BB * HH * UU * 4;
    float* partial = (float*)w; w += (size_t)BH * 16 * UU * DK * 4;
    float* sums    = (float*)w; w += (size_t)BH * 64 * DK * 4;

    // 1) fill attns with 1/L
    fill_attns<<<4096, 256, 0, stream>>>(attns, (long)BB * HH * LL * LL / 4);

    // 2) projections q,k,v
    dim3 g1(4096 / 128, DD / 128, 3);
    proj_gemm<<<g1, 256, 0, stream>>>(x, Wq, bq, Wk, bk, Wv, bv, q, k, v);

    // 3) sampled QK^T -> M
    qk_sample_M<<<BH * (LL / 64), 256, 0, stream>>>(q, k, idxs, M);

    // 4) top-40 indices per (b,h)
    topk_M<<<BH, 256, 0, stream>>>(M, Mtop);

    // 5) raw scores into attns rows
    scores_topq<<<BH * 16, 256, 0, stream>>>(q, k, Mtop, attns);

    // 6) softmax in place on the selected rows
    softmax_rows<<<BH * UU, 256, 0, stream>>>(Mtop, attns);

    // 7) upd = attn @ v, split over 16 l-chunks
    upd_partial<<<BH * 16, 256, 0, stream>>>(v, Mtop, attns, partial);

    // 8) context = cumsum(v), 3-phase
    dim3 gc(BH, 16);
    cumsum_p1<<<gc, 256, 0, stream>>>(v, sums);
    cumsum_p2<<<BH, 64, 0, stream>>>(sums);
    cumsum_p3<<<gc, 256, 0, stream>>>(v, sums, ctx);

    // 9) reduce partials, scatter into ctx
    reduce_scatter<<<BH * UU, 64, 0, stream>>>(Mtop, partial, ctx);
}